// Round 1
// baseline (1659.075 us; speedup 1.0000x reference)
//
#include <hip/hip_runtime.h>

// ---------------------------------------------------------------------------
// FullTensorProductSparse: irreps1 = 32x(l=0,1,2), irreps2 = 1x(l=0,1,2)
// input1: (N,288) chunk layout per l: offset {0,32,128}, chunk reshaped (d1, 32)
//   -> element index = off1 + m*32 + u
// input2: (N,9) offsets {0,1,4}
// output: (N,2592), chunks ordered by e3nn sort (see c_ostart/c_opath below)
// out[u,o] = sum_m x1[m,u] * w[m,o],  w[m,o] = sum_n cg[m,n,o]*x2[n]
// CG tables generated on-device each launch (Racah + real-SH basis change).
// ---------------------------------------------------------------------------

#define NPATH 19

__device__ const int c_l1[NPATH]    = {0,0,0,1,1,1,1,1,1,1,2,2,2,2,2,2,2,2,2};
__device__ const int c_l2[NPATH]    = {0,1,2,0,1,1,1,2,2,2,0,1,1,1,2,2,2,2,2};
__device__ const int c_l3[NPATH]    = {0,1,2,1,0,1,2,1,2,3,2,1,2,3,0,1,2,3,4};
__device__ const int c_x1off[NPATH] = {0,0,0,32,32,32,32,32,32,32,128,128,128,128,128,128,128,128,128};
__device__ const int c_x2off[NPATH] = {0,1,4,0,1,1,1,4,4,4,0,1,1,1,4,4,4,4,4};
// cumulative d1*d2*d3
__device__ const int c_cgbase[NPATH]= {0,1,10,35,44,53,80,125,170,245,350,375,420,495,600,625,700,825,1000};
// cumulative d1*d3
__device__ const int c_wbase[NPATH] = {0,1,4,9,18,21,30,45,54,69,90,115,130,155,190,195,210,235,270};
// output ordering: sorted chunk start offsets and which path lives there
__device__ const int c_ostart[NPATH]= {0,32,64,96,192,288,384,480,576,672,832,992,1152,1312,1472,1632,1856,2080,2304};
__device__ const int c_opath[NPATH] = {0,4,14,1,3,7,11,5,15,2,6,10,16,8,12,9,13,17,18};

__device__ float    g_cg[1225];
__device__ unsigned g_wdesc[315];
__device__ __align__(16) unsigned g_odesc[2592];

__device__ __forceinline__ int imax(int a, int b){ return a > b ? a : b; }
__device__ __forceinline__ int imin(int a, int b){ return a < b ? a : b; }

__device__ double dfact(int n){ double r = 1.0; for (int i = 2; i <= n; ++i) r *= (double)i; return r; }

__device__ double su2_cg(int j1,int m1,int j2,int m2,int j3,int m3){
  if (m3 != m1 + m2) return 0.0;
  int vmin = imax(imax(-j1 + j2 + m3, -j1 + m1), 0);
  int vmax = imin(imin(j2 + j3 + m1, j3 - j1 + j2), j3 + m3);
  if (vmax < vmin) return 0.0;
  double C = sqrt((2.0*j3 + 1.0) * dfact(j3 + j1 - j2) * dfact(j3 - j1 + j2) * dfact(j1 + j2 - j3)
                  * dfact(j3 + m3) * dfact(j3 - m3)
                  / (dfact(j1 + j2 + j3 + 1) * dfact(j1 - m1) * dfact(j1 + m1)
                     * dfact(j2 - m2) * dfact(j2 + m2)));
  double S = 0.0;
  for (int v = vmin; v <= vmax; ++v){
    double term = dfact(j2 + j3 + m1 - v) * dfact(j1 - m1 + v)
                / (dfact(v) * dfact(j3 - j1 + j2 - v) * dfact(j3 + m3 - v) * dfact(v + j1 - j2 - m3));
    S += ((v + j2 + m2) & 1) ? -term : term;
  }
  return C * S;
}

// entry (row, col) of the real->complex SH change-of-basis matrix q(l), e3nn convention
__device__ void qent(int l, int row, int col, double* qr, double* qi){
  double br = 0.0, bi = 0.0;
  const double s = 0.70710678118654752440;
  int m = row - l;
  if (m < 0){
    if (col == l - m)      br = s;      // l + |m|
    else if (col == l + m) bi = -s;     // l - |m|
  } else if (m == 0){
    if (col == l) br = 1.0;
  } else {
    double sg = (m & 1) ? -1.0 : 1.0;
    if (col == l + m)      br = sg * s;
    else if (col == l - m) bi = sg * s;
  }
  // multiply by (-i)^l
  double pr, pi;
  switch (l & 3){
    case 0:  pr = 1.0;  pi = 0.0;  break;
    case 1:  pr = 0.0;  pi = -1.0; break;
    case 2:  pr = -1.0; pi = 0.0;  break;
    default: pr = 0.0;  pi = 1.0;  break;
  }
  *qr = br * pr - bi * pi;
  *qi = br * pi + bi * pr;
}

__global__ __launch_bounds__(256) void init_kernel(){
  __shared__ double cgs[1225];
  __shared__ double norms[NPATH];
  int t = threadIdx.x;

  // unnormalized real wigner-3j entries
  for (int e = t; e < 1225; e += 256){
    int p = 0;
    while (p + 1 < NPATH && c_cgbase[p + 1] <= e) ++p;
    int l1 = c_l1[p], l2 = c_l2[p], l3 = c_l3[p];
    int d1 = 2*l1 + 1, d2 = 2*l2 + 1, d3 = 2*l3 + 1;
    int loc = e - c_cgbase[p];
    int o = loc % d3;
    int n = (loc / d3) % d2;
    int m = loc / (d3 * d2);
    double accr = 0.0;
    for (int i = 0; i < d1; ++i){
      double q1r, q1i; qent(l1, i, m, &q1r, &q1i);
      if (q1r == 0.0 && q1i == 0.0) continue;
      for (int k = 0; k < d2; ++k){
        double q2r, q2i; qent(l2, k, n, &q2r, &q2i);
        if (q2r == 0.0 && q2i == 0.0) continue;
        double ar = q1r*q2r - q1i*q2i;
        double ai = q1r*q2i + q1i*q2r;
        for (int mm = 0; mm < d3; ++mm){
          double q3r, q3i; qent(l3, mm, o, &q3r, &q3i);
          if (q3r == 0.0 && q3i == 0.0) continue;
          double cg = su2_cg(l1, i - l1, l2, k - l2, l3, mm - l3);
          if (cg == 0.0) continue;
          // real( (q1*q2) * conj(q3) ) * cg
          accr += (ar*q3r + ai*q3i) * cg;
        }
      }
    }
    cgs[e] = accr;
  }
  __syncthreads();

  if (t < NPATH){
    int p = t;
    int sz = ((p + 1 < NPATH) ? c_cgbase[p + 1] : 1225) - c_cgbase[p];
    double s = 0.0;
    for (int j = 0; j < sz; ++j){ double v = cgs[c_cgbase[p] + j]; s += v * v; }
    norms[p] = sqrt(s);
  }
  __syncthreads();

  for (int e = t; e < 1225; e += 256){
    int p = 0;
    while (p + 1 < NPATH && c_cgbase[p + 1] <= e) ++p;
    double scale = sqrt((double)(2 * c_l3[p] + 1)) / norms[p];
    g_cg[e] = (float)(cgs[e] * scale);
  }

  // w descriptors: w[p][m][o] = sum_n cg[cgstart + d3*n] * x2s[x2off + n]
  for (int w = t; w < 315; w += 256){
    int p = 0;
    while (p + 1 < NPATH && c_wbase[p + 1] <= w) ++p;
    int l2 = c_l2[p], l3 = c_l3[p];
    int d2 = 2*l2 + 1, d3 = 2*l3 + 1;
    int loc = w - c_wbase[p];
    int o = loc % d3;
    int m = loc / d3;
    unsigned cgstart = (unsigned)(c_cgbase[p] + m * d2 * d3 + o);
    g_wdesc[w] = cgstart | ((unsigned)c_x2off[p] << 11) | ((unsigned)d2 << 15) | ((unsigned)d3 << 18);
  }

  // out descriptors: out[k] = sum_m x1s[a + 32*m] * ws[b + d3*m]
  for (int k = t; k < 2592; k += 256){
    int s = 0;
    while (s + 1 < NPATH && c_ostart[s + 1] <= k) ++s;
    int p = c_opath[s];
    int l1 = c_l1[p], l3 = c_l3[p];
    int d1 = 2*l1 + 1, d3 = 2*l3 + 1;
    int loc = k - c_ostart[s];
    int u = loc / d3;
    int o = loc % d3;
    unsigned a = (unsigned)(c_x1off[p] + u);
    unsigned b = (unsigned)(c_wbase[p] + o);
    g_odesc[k] = a | (b << 9) | ((unsigned)d1 << 18) | ((unsigned)d3 << 21);
  }
}

__global__ __launch_bounds__(256) void tp_kernel(const float* __restrict__ x1g,
                                                 const float* __restrict__ x2g,
                                                 float* __restrict__ out, int N){
  __shared__ float x1s[288];
  __shared__ float x2s[12];
  __shared__ float ws[316];
  int t = threadIdx.x;

  for (int row = blockIdx.x; row < N; row += gridDim.x){
    // stage inputs
    if (t < 72){
      ((float4*)x1s)[t] = ((const float4*)(x1g + (size_t)row * 288))[t];
    } else if (t >= 96 && t < 105){
      x2s[t - 96] = x2g[(size_t)row * 9 + (t - 96)];
    }
    __syncthreads();

    // per-row w coefficients
    for (int w = t; w < 315; w += 256){
      unsigned d = g_wdesc[w];
      int cgi = d & 2047;
      int x2o = (d >> 11) & 15;
      int d2  = (d >> 15) & 7;
      int d3  = (d >> 18) & 15;
      float acc = 0.f;
      for (int n = 0; n < d2; ++n) acc += g_cg[cgi + d3 * n] * x2s[x2o + n];
      ws[w] = acc;
    }
    __syncthreads();

    // outputs, float4-vectorized coalesced stores
    float4* outv = (float4*)(out + (size_t)row * 2592);
    for (int kv = t; kv < 648; kv += 256){
      int k = kv * 4;
      uint4 dd = ((const uint4*)g_odesc)[kv];
      unsigned dj[4] = {dd.x, dd.y, dd.z, dd.w};
      float r[4];
      (void)k;
      #pragma unroll
      for (int j = 0; j < 4; ++j){
        unsigned d = dj[j];
        int a  = d & 511;
        int b  = (d >> 9) & 511;
        int d1 = (d >> 18) & 7;
        int d3 = (d >> 21) & 15;
        float acc = x1s[a] * ws[b];
        for (int m = 1; m < d1; ++m) acc += x1s[a + 32 * m] * ws[b + d3 * m];
        r[j] = acc;
      }
      float4 rv; rv.x = r[0]; rv.y = r[1]; rv.z = r[2]; rv.w = r[3];
      outv[kv] = rv;
    }
    __syncthreads();
  }
}

extern "C" void kernel_launch(void* const* d_in, const int* in_sizes, int n_in,
                              void* d_out, int out_size, void* d_ws, size_t ws_size,
                              hipStream_t stream) {
  const float* x1 = (const float*)d_in[0];
  const float* x2 = (const float*)d_in[1];
  float* out = (float*)d_out;
  int N = in_sizes[0] / 288;   // 100000

  hipLaunchKernelGGL(init_kernel, dim3(1), dim3(256), 0, stream);

  int grid = (N < 25000) ? (N > 0 ? N : 1) : 25000;  // 4 rows/block at N=100000
  hipLaunchKernelGGL(tp_kernel, dim3(grid), dim3(256), 0, stream, x1, x2, out, N);
}